// Round 1
// baseline (829.139 us; speedup 1.0000x reference)
//
#include <hip/hip_runtime.h>
#include <math.h>

#define NB 512
#define NPC 32
#define KNN 12
#define DD 64
#define NL 4
#define NN (NB*NPC)

__device__ __forceinline__ float silu_f(float x) {
    return x / (1.0f + __expf(-x));
}

// out[r][lane] accumulation: A rows in LDS (k-contiguous, 16B aligned stride),
// W in global [K][64] (row-major, lane-coalesced, L1/L2-resident).
template<int R>
__device__ __forceinline__ void gemm_acc(const float* A, int astride,
                                         const float* __restrict__ Wg,
                                         int K, int lane, float* acc) {
#pragma unroll 2
    for (int kq = 0; kq < (K >> 2); ++kq) {
        float w0 = Wg[(4*kq+0)*64 + lane];
        float w1 = Wg[(4*kq+1)*64 + lane];
        float w2 = Wg[(4*kq+2)*64 + lane];
        float w3 = Wg[(4*kq+3)*64 + lane];
#pragma unroll
        for (int r = 0; r < R; ++r) {
            float4 a = *(const float4*)(A + r*astride + 4*kq);
            acc[r] = fmaf(a.x, w0, acc[r]);
            acc[r] = fmaf(a.y, w1, acc[r]);
            acc[r] = fmaf(a.z, w2, acc[r]);
            acc[r] = fmaf(a.w, w3, acc[r]);
        }
    }
}

extern "C" __global__ __launch_bounds__(256, 2)
void crystal_fused(const float* __restrict__ z_nodes, const float* __restrict__ t_in,
                   const float* __restrict__ frac,    const float* __restrict__ lattice,
                   const float* __restrict__ time_w1, const float* __restrict__ time_b1,
                   const float* __restrict__ time_w2, const float* __restrict__ time_b2,
                   const float* __restrict__ emb_w,   const float* __restrict__ emb_b,
                   const float* __restrict__ edge_w1, const float* __restrict__ edge_b1,
                   const float* __restrict__ edge_w2, const float* __restrict__ edge_b2,
                   const float* __restrict__ coord_w1,const float* __restrict__ coord_b1,
                   const float* __restrict__ coord_w2,
                   const float* __restrict__ node_w1, const float* __restrict__ node_b1,
                   const float* __restrict__ node_w2, const float* __restrict__ node_b2,
                   float* __restrict__ out)
{
    __shared__ float s_h [32][64];
    __shared__ float s_hs[32][64];      // h@W1a ; reused as n1 in node phase
    __shared__ float s_hd[32][64];      // h@W1b + tb
    __shared__ float s_big[48*64*2];    // m1/m2 chunks; overlaid: dist-cart matrix, z staging
    __shared__ float s_mi[32][64];
    __shared__ float s_dsq[32][33];     // +1 pad: knn scans read columns
    __shared__ float s_ndc[32][KNN][3];
    __shared__ float s_ndsq[32][KNN];
    __shared__ int   s_nbr[32][KNN];
    __shared__ float s_frac[32][3];
    __shared__ float s_lat[9];
    __shared__ float s_inv[9];
    __shared__ float s_sinu[64];
    __shared__ float s_t1[128];
    __shared__ float s_tf[64];
    __shared__ float s_shift[32][3];

    const int c    = blockIdx.x;
    const int tid  = threadIdx.x;
    const int lane = tid & 63;
    const int wave = tid >> 6;
    const int base = c * NPC;

    // ---------------- phase 0: small loads + sinusoidal embedding ----------------
    if (tid < 96) {
        ((float*)s_frac)[tid] = frac[base*3 + tid];
    } else if (tid < 105) {
        s_lat[tid-96] = lattice[c*9 + (tid-96)];
    } else if (tid >= 128 && tid < 160) {
        int i = tid - 128;
        float freq = expf((float)i * (-9.210340371976184f / 31.0f)); // -ln(1e4)/31
        float ang  = t_in[c] * freq;
        s_sinu[i]     = sinf(ang);
        s_sinu[i+32]  = cosf(ang);
    }
    __syncthreads();

    // ---------------- phase 1: PBC pair distances (+ cart diffs in s_big) ----------------
    float* dcf = s_big;                  // [1024][3]
    {
        float l00=s_lat[0],l01=s_lat[1],l02=s_lat[2];
        float l10=s_lat[3],l11=s_lat[4],l12=s_lat[5];
        float l20=s_lat[6],l21=s_lat[7],l22=s_lat[8];
        for (int p = tid; p < 1024; p += 256) {
            int i = p >> 5, j = p & 31;
            float dx = s_frac[i][0]-s_frac[j][0];
            float dy = s_frac[i][1]-s_frac[j][1];
            float dz = s_frac[i][2]-s_frac[j][2];
            dx -= rintf(dx); dy -= rintf(dy); dz -= rintf(dz);
            float cx = dx*l00 + dy*l10 + dz*l20;
            float cy = dx*l01 + dy*l11 + dz*l21;
            float cz = dx*l02 + dy*l12 + dz*l22;
            float dd = cx*cx + cy*cy + cz*cz;
            s_dsq[i][j] = (i==j) ? 3.0e38f : dd;
            dcf[p*3+0]=cx; dcf[p*3+1]=cy; dcf[p*3+2]=cz;
        }
    }
    __syncthreads();

    // ---------------- phase 2: KNN select (tid<32)  ||  time-MLP layer 1 (tid>=128) ----------------
    if (tid < 32) {
        int i = tid;
        for (int k = 0; k < KNN; ++k) {
            float best = 3.9e38f; int bj = 0;
            for (int j = 0; j < 32; ++j) {
                float v = s_dsq[i][j];
                if (v < best) { best = v; bj = j; }   // strict < : lowest index wins ties (matches top_k)
            }
            s_dsq[i][bj] = 3.9e38f;
            s_nbr[i][k]  = bj;
            s_ndsq[i][k] = best;
            int p = (i<<5) + bj;
            s_ndc[i][k][0] = dcf[p*3+0];
            s_ndc[i][k][1] = dcf[p*3+1];
            s_ndc[i][k][2] = dcf[p*3+2];
        }
    } else if (tid >= 128) {
        int jj = tid - 128;
        float acc = time_b1[jj];
        for (int k = 0; k < 64; ++k) acc = fmaf(s_sinu[k], time_w1[k*128+jj], acc);
        s_t1[jj] = silu_f(acc);
    }
    __syncthreads();

    // ---------------- phase 3: t_feat ; zero shift ----------------
    if (tid < 64) {
        float acc = time_b2[tid];
        for (int k = 0; k < 128; ++k) acc = fmaf(s_t1[k], time_w2[k*64+tid], acc);
        s_tf[tid] = acc;
    } else if (tid < 160) {
        ((float*)s_shift)[tid-64] = 0.0f;
    }
    __syncthreads();

    // ---------------- phase 4: node embedding h0 = z @ emb_w + b ----------------
    float* zbuf = s_big;                 // [32][128]
    for (int q = tid; q < 4096; q += 256) zbuf[q] = z_nodes[base*128 + q];
    __syncthreads();
    {
        float acc[8];
#pragma unroll
        for (int r = 0; r < 8; ++r) acc[r] = emb_b[lane];
        gemm_acc<8>(zbuf + (wave*8)*128, 128, emb_w, 128, lane, acc);
#pragma unroll
        for (int r = 0; r < 8; ++r) s_h[wave*8+r][lane] = acc[r];
    }
    __syncthreads();

    // ---------------- EGNN layers ----------------
    for (int l = 0; l < NL; ++l) {
        const float* W1a = edge_w1 + l*193*64;
        const float* W1b = W1a + 64*64;
        const float  w1d = W1a[128*64 + lane];       // dist^2 row
        const float* W1t = W1a + 129*64;
        const float* W2  = edge_w2  + l*4096;
        const float* Wc1 = coord_w1 + l*4096;
        const float  b2e = edge_b2 [l*64 + lane];
        const float  cb1 = coord_b1[l*64 + lane];
        const float  w2c = coord_w2[l*64 + lane];
        const float* Wnh = node_w1 + l*192*64;
        const float* Wnm = Wnh + 64*64;
        const float* Wnt = Wnh + 128*64;
        const float* Wn2 = node_w2 + l*4096;
        const float  nb2 = node_b2[l*64 + lane];

        // per-crystal t-terms (redundant per wave; 128 fmacs)
        float tb    = edge_b1[l*64 + lane];
        float nbase = node_b1[l*64 + lane];
        for (int k = 0; k < 64; ++k) {
            tb    = fmaf(s_tf[k], W1t[k*64 + lane], tb);
            nbase = fmaf(s_tf[k], Wnt[k*64 + lane], nbase);
        }

        // ---- step A: hs = h@W1a ; hd = h@W1b + tb ; zero m_i ----
        {
            float acc[8], accd[8];
#pragma unroll
            for (int r = 0; r < 8; ++r) { acc[r] = 0.f; accd[r] = tb; }
            gemm_acc<8>(&s_h[wave*8][0], 64, W1a, 64, lane, acc);
            gemm_acc<8>(&s_h[wave*8][0], 64, W1b, 64, lane, accd);
#pragma unroll
            for (int r = 0; r < 8; ++r) {
                s_hs[wave*8+r][lane] = acc[r];
                s_hd[wave*8+r][lane] = accd[r];
                s_mi[wave*8+r][lane] = 0.f;
            }
        }
        __syncthreads();

        // ---- edge phase: each wave owns one dst node per iteration (12 edges) ----
        float* m1w = s_big +        (wave*12)*64;
        float* m2w = s_big + 3072 + (wave*12)*64;
        for (int it = 0; it < 8; ++it) {
            int dst = it*4 + wave;
            float hd_d = s_hd[dst][lane];
#pragma unroll
            for (int j = 0; j < KNN; ++j) {
                int src = s_nbr[dst][j];
                float pre = s_hs[src][lane] + hd_d + s_ndsq[dst][j]*w1d;
                m1w[j*64 + lane] = silu_f(pre);
            }
            __syncthreads();
            float acc[KNN];
#pragma unroll
            for (int r = 0; r < KNN; ++r) acc[r] = b2e;
            gemm_acc<KNN>(m1w, 64, W2, 64, lane, acc);
            float misum = 0.f;
#pragma unroll
            for (int r = 0; r < KNN; ++r) {
                float v = silu_f(acc[r]);
                m2w[r*64+lane] = v;
                misum += v;
            }
            s_mi[dst][lane] += misum;
            __syncthreads();
            float acc2[KNN];
#pragma unroll
            for (int r = 0; r < KNN; ++r) acc2[r] = cb1;
            gemm_acc<KNN>(m2w, 64, Wc1, 64, lane, acc2);
#pragma unroll
            for (int r = 0; r < KNN; ++r) {
                float v = silu_f(acc2[r]) * w2c;
                v += __shfl_xor(v, 1);
                v += __shfl_xor(v, 2);
                v += __shfl_xor(v, 4);
                v += __shfl_xor(v, 8);
                v += __shfl_xor(v, 16);
                v += __shfl_xor(v, 32);
                if (lane == 0) {
                    int src = s_nbr[dst][r];
                    atomicAdd(&s_shift[src][0], s_ndc[dst][r][0]*v);
                    atomicAdd(&s_shift[src][1], s_ndc[dst][r][1]*v);
                    atomicAdd(&s_shift[src][2], s_ndc[dst][r][2]*v);
                }
            }
        }
        __syncthreads();

        // ---- node phase: h += silu([h|m_i|t]@Wn1+b1)@Wn2 + b2 ----
        {
            float acc[8];
#pragma unroll
            for (int r = 0; r < 8; ++r) acc[r] = nbase;
            gemm_acc<8>(&s_h [wave*8][0], 64, Wnh, 64, lane, acc);
            gemm_acc<8>(&s_mi[wave*8][0], 64, Wnm, 64, lane, acc);
#pragma unroll
            for (int r = 0; r < 8; ++r) s_hs[wave*8+r][lane] = silu_f(acc[r]);  // n1
        }
        __syncthreads();
        {
            float acc[8];
#pragma unroll
            for (int r = 0; r < 8; ++r) acc[r] = nb2;
            gemm_acc<8>(&s_hs[wave*8][0], 64, Wn2, 64, lane, acc);
#pragma unroll
            for (int r = 0; r < 8; ++r) s_h[wave*8+r][lane] += acc[r];
        }
        __syncthreads();
    }

    // ---------------- epilogue: shift_frac = shift @ inv(lattice) ; write h ----------------
    if (tid == 0) {
        float a=s_lat[0],b=s_lat[1],cc=s_lat[2];
        float d=s_lat[3],e=s_lat[4],f =s_lat[5];
        float g=s_lat[6],h2=s_lat[7],i2=s_lat[8];
        float A  =  (e*i2 - f*h2);
        float Bm = -(d*i2 - f*g);
        float C  =  (d*h2 - e*g);
        float det = a*A + b*Bm + cc*C;
        float rd = 1.0f/det;
        s_inv[0] = A*rd;
        s_inv[1] = -(b*i2 - cc*h2)*rd;
        s_inv[2] =  (b*f  - cc*e )*rd;
        s_inv[3] = Bm*rd;
        s_inv[4] =  (a*i2 - cc*g )*rd;
        s_inv[5] = -(a*f  - cc*d )*rd;
        s_inv[6] = C*rd;
        s_inv[7] = -(a*h2 - b*g  )*rd;
        s_inv[8] =  (a*e  - b*d  )*rd;
    }
    __syncthreads();
    if (tid < 96) {
        int r = tid/3, j = tid%3;
        float v = s_shift[r][0]*s_inv[0*3+j]
                + s_shift[r][1]*s_inv[1*3+j]
                + s_shift[r][2]*s_inv[2*3+j];
        out[(base + r)*3 + j] = v;
    }
    for (int q = tid; q < 2048; q += 256) {
        out[NN*3 + base*64 + q] = ((float*)s_h)[q];
    }
}

extern "C" void kernel_launch(void* const* d_in, const int* in_sizes, int n_in,
                              void* d_out, int out_size, void* d_ws, size_t ws_size,
                              hipStream_t stream) {
    crystal_fused<<<NB, 256, 0, stream>>>(
        (const float*)d_in[0],  (const float*)d_in[1],  (const float*)d_in[2],  (const float*)d_in[3],
        (const float*)d_in[6],  (const float*)d_in[7],  (const float*)d_in[8],  (const float*)d_in[9],
        (const float*)d_in[10], (const float*)d_in[11],
        (const float*)d_in[12], (const float*)d_in[13], (const float*)d_in[14], (const float*)d_in[15],
        (const float*)d_in[16], (const float*)d_in[17], (const float*)d_in[18],
        (const float*)d_in[19], (const float*)d_in[20], (const float*)d_in[21], (const float*)d_in[22],
        (float*)d_out);
}

// Round 2
// 451.104 us; speedup vs baseline: 1.8380x; 1.8380x over previous
//
#include <hip/hip_runtime.h>
#include <math.h>

#define NB 512
#define NPC 32
#define KNN 12
#define NL 4
#define NN (NB*NPC)
#define WPL 28672   // prepacked bf16 weight elems per layer

typedef float v4f __attribute__((ext_vector_type(4)));
typedef short s8v __attribute__((ext_vector_type(8)));

__device__ __forceinline__ float silu_f(float x) { return x / (1.0f + __expf(-x)); }

__device__ __forceinline__ unsigned short f2bf(float x) {
    unsigned u = __float_as_uint(x);
    u += 0x7fffu + ((u >> 16) & 1u);
    return (unsigned short)(u >> 16);
}

// fp32 fallback GEMM (embedding only): A rows broadcast from LDS, W coalesced global
template<int R>
__device__ __forceinline__ void gemm_acc(const float* A, int astride,
                                         const float* __restrict__ Wg,
                                         int K, int lane, float* acc) {
#pragma unroll 2
    for (int kq = 0; kq < (K >> 2); ++kq) {
        float w0 = Wg[(4*kq+0)*64 + lane];
        float w1 = Wg[(4*kq+1)*64 + lane];
        float w2 = Wg[(4*kq+2)*64 + lane];
        float w3 = Wg[(4*kq+3)*64 + lane];
#pragma unroll
        for (int r = 0; r < R; ++r) {
            float4 a = *(const float4*)(A + r*astride + 4*kq);
            acc[r] = fmaf(a.x, w0, acc[r]);
            acc[r] = fmaf(a.y, w1, acc[r]);
            acc[r] = fmaf(a.z, w2, acc[r]);
            acc[r] = fmaf(a.w, w3, acc[r]);
        }
    }
}

// ---------------- prepack: fp32 weights -> bf16 B-fragments in mfma lane order ----------------
// frag elem j of lane for (ntile,ktile) = W[ktile*32 + (lane>>4)*8 + j][ntile*16 + (lane&15)]
// per-layer layout: W1ab(8 nt x 2 kt)=8192 | W2=4096 | Wc1=4096 | Wn1(4 nt x 4 kt)=8192 | Wn2=4096
extern "C" __global__ void prepack_w(const float* __restrict__ edge_w1, const float* __restrict__ edge_w2,
                                     const float* __restrict__ coord_w1, const float* __restrict__ node_w1,
                                     const float* __restrict__ node_w2, unsigned short* __restrict__ wout) {
    int tid = blockIdx.x * 256 + threadIdx.x;
    if (tid >= 4 * WPL) return;
    int l = tid / WPL, r = tid % WPL;
    int base, nKt, mat;
    if      (r < 8192)  { base = 0;     nKt = 2; mat = 0; }
    else if (r < 12288) { base = 8192;  nKt = 2; mat = 1; }
    else if (r < 16384) { base = 12288; nKt = 2; mat = 2; }
    else if (r < 24576) { base = 16384; nKt = 4; mat = 3; }
    else                { base = 24576; nKt = 2; mat = 4; }
    int idx = r - base;
    int j = idx & 7, lane = (idx >> 3) & 63, t = idx >> 9;
    int kt = t % nKt, nt = t / nKt;
    int k = kt*32 + ((lane >> 4) & 3)*8 + j;
    int n = nt*16 + (lane & 15);
    float v;
    if (mat == 0) v = (n < 64) ? edge_w1[l*193*64 + k*64 + n] : edge_w1[l*193*64 + (64+k)*64 + (n-64)];
    else if (mat == 1) v = edge_w2 [l*4096 + k*64 + n];
    else if (mat == 2) v = coord_w1[l*4096 + k*64 + n];
    else if (mat == 3) v = node_w1 [l*192*64 + k*64 + n];
    else               v = node_w2 [l*4096 + k*64 + n];
    wout[tid] = f2bf(v);
}

// ---------------- main fused kernel: one block per crystal ----------------
extern "C" __global__ __launch_bounds__(256, 2)
void crystal_fused(const float* __restrict__ z_nodes, const float* __restrict__ t_in,
                   const float* __restrict__ frac,    const float* __restrict__ lattice,
                   const float* __restrict__ time_w1, const float* __restrict__ time_b1,
                   const float* __restrict__ time_w2, const float* __restrict__ time_b2,
                   const float* __restrict__ emb_w,   const float* __restrict__ emb_b,
                   const float* __restrict__ edge_w1, const float* __restrict__ edge_b1,
                   const float* __restrict__ edge_b2, const float* __restrict__ coord_b1,
                   const float* __restrict__ coord_w2,
                   const float* __restrict__ node_w1, const float* __restrict__ node_b1,
                   const float* __restrict__ node_b2,
                   const unsigned short* __restrict__ wbf,
                   float* __restrict__ out)
{
    __shared__ float s_h[32*64];                                   // fp32 master h
    __shared__ __align__(16) unsigned short s_habf[32*136];        // bf16 [h | m_i], stride 136
    __shared__ __align__(16) unsigned short s_n1bf[32*72];         // bf16 n1, stride 72
    __shared__ float s_hs[32*65];
    __shared__ float s_hd[32*65];
    __shared__ float s_mi[32*64];
    __shared__ __align__(16) unsigned short s_tiles16[4*2304];     // per-wave m1/m2 tiles; overlaid dcf/zbuf
    __shared__ float s_dsq[32][33];
    __shared__ int   s_esrc[384];
    __shared__ float s_edsq[384];
    __shared__ float s_endc[384*3];
    __shared__ float s_frac[32][3];
    __shared__ float s_lat[9], s_inv[9];
    __shared__ float s_sinu[64], s_t1[128], s_tf[64];
    __shared__ float s_tb[64], s_nb[64];
    __shared__ float s_shift[32*3];

    const int c    = blockIdx.x;
    const int tid  = threadIdx.x;
    const int lane = tid & 63;
    const int wave = tid >> 6;
    const int q4   = lane >> 4;
    const int c16  = lane & 15;
    const int base = c * NPC;

    // ---------------- phase 0: small loads + sinusoidal embedding ----------------
    if (tid < 96) {
        ((float*)s_frac)[tid] = frac[base*3 + tid];
    } else if (tid < 105) {
        s_lat[tid-96] = lattice[c*9 + (tid-96)];
    } else if (tid >= 128 && tid < 160) {
        int i = tid - 128;
        float freq = expf((float)i * (-9.210340371976184f / 31.0f));
        float ang  = t_in[c] * freq;
        s_sinu[i]    = sinf(ang);
        s_sinu[i+32] = cosf(ang);
    }
    __syncthreads();

    // ---------------- phase 1: PBC pair distances ----------------
    float* dcf = (float*)s_tiles16;      // [1024][3]
    {
        float l00=s_lat[0],l01=s_lat[1],l02=s_lat[2];
        float l10=s_lat[3],l11=s_lat[4],l12=s_lat[5];
        float l20=s_lat[6],l21=s_lat[7],l22=s_lat[8];
        for (int p = tid; p < 1024; p += 256) {
            int i = p >> 5, j = p & 31;
            float dx = s_frac[i][0]-s_frac[j][0];
            float dy = s_frac[i][1]-s_frac[j][1];
            float dz = s_frac[i][2]-s_frac[j][2];
            dx -= rintf(dx); dy -= rintf(dy); dz -= rintf(dz);
            float cx = dx*l00 + dy*l10 + dz*l20;
            float cy = dx*l01 + dy*l11 + dz*l21;
            float cz = dx*l02 + dy*l12 + dz*l22;
            float dd = cx*cx + cy*cy + cz*cz;
            s_dsq[i][j] = (i==j) ? 3.0e38f : dd;
            dcf[p*3+0]=cx; dcf[p*3+1]=cy; dcf[p*3+2]=cz;
        }
    }
    __syncthreads();

    // ---------------- phase 2: KNN (tid<32) || time-MLP layer 1 (tid>=128) ----------------
    if (tid < 32) {
        int i = tid;
        for (int k = 0; k < KNN; ++k) {
            float best = 3.9e38f; int bj = 0;
            for (int j = 0; j < 32; ++j) {
                float v = s_dsq[i][j];
                if (v < best) { best = v; bj = j; }
            }
            s_dsq[i][bj] = 3.9e38f;
            int e = i*KNN + k;
            s_esrc[e] = bj;
            s_edsq[e] = best;
            int p = (i<<5) + bj;
            s_endc[e*3+0] = dcf[p*3+0];
            s_endc[e*3+1] = dcf[p*3+1];
            s_endc[e*3+2] = dcf[p*3+2];
        }
    } else if (tid >= 128) {
        int jj = tid - 128;
        float acc = time_b1[jj];
        for (int k = 0; k < 64; ++k) acc = fmaf(s_sinu[k], time_w1[k*128+jj], acc);
        s_t1[jj] = silu_f(acc);
    }
    __syncthreads();

    // ---------------- phase 3: t_feat ; zero shift ----------------
    if (tid < 64) {
        float acc = time_b2[tid];
        for (int k = 0; k < 128; ++k) acc = fmaf(s_t1[k], time_w2[k*64+tid], acc);
        s_tf[tid] = acc;
    } else if (tid < 160) {
        s_shift[tid-64] = 0.0f;
    }
    __syncthreads();

    // ---------------- phase 4: node embedding h0 = z @ emb_w + b ----------------
    float* zbuf = (float*)s_tiles16;     // [32][128]
    for (int q = tid; q < 4096; q += 256) zbuf[q] = z_nodes[base*128 + q];
    __syncthreads();
    {
        float acc[8];
#pragma unroll
        for (int r = 0; r < 8; ++r) acc[r] = emb_b[lane];
        gemm_acc<8>(zbuf + (wave*8)*128, 128, emb_w, 128, lane, acc);
#pragma unroll
        for (int r = 0; r < 8; ++r) {
            int row = wave*8 + r;
            s_h[row*64 + lane] = acc[r];
            s_habf[row*136 + lane] = f2bf(acc[r]);
        }
    }

    // ---------------- EGNN layers (MFMA) ----------------
    for (int l = 0; l < NL; ++l) {
        const unsigned short* wl = wbf + l*WPL;
        const float* W1t = edge_w1 + l*193*64 + 129*64;
        const float* Wnt = node_w1 + l*192*64 + 128*64;
        const float  w1d = edge_w1[l*193*64 + 128*64 + lane];
        float b2e_v[4], cb1_v[4], w2c_v[4];
#pragma unroll
        for (int nt = 0; nt < 4; ++nt) {
            b2e_v[nt] = edge_b2 [l*64 + nt*16 + c16];
            cb1_v[nt] = coord_b1[l*64 + nt*16 + c16];
            w2c_v[nt] = coord_w2[l*64 + nt*16 + c16];
        }
        float nb2_v = node_b2[l*64 + wave*16 + c16];

        // per-crystal t-terms + zero m_i (wave-local rows)
        if (wave == 0) {
            float t = edge_b1[l*64 + lane];
            for (int k = 0; k < 64; ++k) t = fmaf(s_tf[k], W1t[k*64 + lane], t);
            s_tb[lane] = t;
        } else if (wave == 1) {
            float t = node_b1[l*64 + lane];
            for (int k = 0; k < 64; ++k) t = fmaf(s_tf[k], Wnt[k*64 + lane], t);
            s_nb[lane] = t;
        }
#pragma unroll
        for (int r = 0; r < 8; ++r) s_mi[(wave*8+r)*64 + lane] = 0.0f;
        __syncthreads();    // B1: habf(prev layer), tb, nb, mi-zero visible

        // ---- step A: [hs|hd] = h @ [W1a|W1b] (+tb on hd), wave w -> ntiles 2w,2w+1 ----
        {
            s8v a[2][2];
#pragma unroll
            for (int mt = 0; mt < 2; ++mt)
#pragma unroll
                for (int kt = 0; kt < 2; ++kt)
                    a[mt][kt] = *(const s8v*)(s_habf + (mt*16 + c16)*136 + kt*32 + q4*8);
#pragma unroll
            for (int nt2 = 0; nt2 < 2; ++nt2) {
                int nt = wave*2 + nt2;
                v4f acc[2] = {{0.f,0.f,0.f,0.f},{0.f,0.f,0.f,0.f}};
#pragma unroll
                for (int kt = 0; kt < 2; ++kt) {
                    s8v b = *(const s8v*)(wl + ((nt*2+kt)*64 + lane)*8);
#pragma unroll
                    for (int mt = 0; mt < 2; ++mt)
                        acc[mt] = __builtin_amdgcn_mfma_f32_16x16x32_bf16(a[mt][kt], b, acc[mt], 0, 0, 0);
                }
                int col = nt*16 + c16;
#pragma unroll
                for (int mt = 0; mt < 2; ++mt)
#pragma unroll
                    for (int reg = 0; reg < 4; ++reg) {
                        int row = mt*16 + q4*4 + reg;
                        if (col < 64) s_hs[row*65 + col] = acc[mt][reg];
                        else          s_hd[row*65 + (col-64)] = acc[mt][reg] + s_tb[col-64];
                    }
            }
        }
        __syncthreads();    // B2: hs/hd visible to all waves

        // ---- edge phase: wave-local, 6 M-tiles of 16 edges each ----
        {
            s8v w2f[8], wc1f[8];
#pragma unroll
            for (int nt = 0; nt < 4; ++nt)
#pragma unroll
                for (int kt = 0; kt < 2; ++kt) {
                    w2f [nt*2+kt] = *(const s8v*)(wl +  8192 + ((nt*2+kt)*64 + lane)*8);
                    wc1f[nt*2+kt] = *(const s8v*)(wl + 12288 + ((nt*2+kt)*64 + lane)*8);
                }
            unsigned short* m1p = s_tiles16 + wave*2304;
            unsigned short* m2p = m1p + 1152;

            for (int m = 0; m < 6; ++m) {
                int e0 = wave*96 + m*16;
                // m1 tile build (lane = col d)
#pragma unroll
                for (int i = 0; i < 16; ++i) {
                    int e = e0 + i;
                    int dst = e / KNN;
                    float x = s_hs[s_esrc[e]*65 + lane] + s_hd[dst*65 + lane] + s_edsq[e]*w1d;
                    m1p[i*72 + lane] = f2bf(silu_f(x));
                }
                asm volatile("s_waitcnt lgkmcnt(0)" ::: "memory");
                s8v a0 = *(const s8v*)(m1p + c16*72 +      q4*8);
                s8v a1 = *(const s8v*)(m1p + c16*72 + 32 + q4*8);
                // m2 = silu(m1@W2 + b2)
#pragma unroll
                for (int nt = 0; nt < 4; ++nt) {
                    v4f acc = {0.f,0.f,0.f,0.f};
                    acc = __builtin_amdgcn_mfma_f32_16x16x32_bf16(a0, w2f[nt*2+0], acc, 0,0,0);
                    acc = __builtin_amdgcn_mfma_f32_16x16x32_bf16(a1, w2f[nt*2+1], acc, 0,0,0);
                    int col = nt*16 + c16;
#pragma unroll
                    for (int reg = 0; reg < 4; ++reg) {
                        int row = q4*4 + reg;
                        float v = silu_f(acc[reg] + b2e_v[nt]);
                        m2p[row*72 + col] = f2bf(v);
                        int dst = (e0 + row) / KNN;
                        atomicAdd(&s_mi[dst*64 + col], v);
                    }
                }
                asm volatile("s_waitcnt lgkmcnt(0)" ::: "memory");
                s8v c0 = *(const s8v*)(m2p + c16*72 +      q4*8);
                s8v c1 = *(const s8v*)(m2p + c16*72 + 32 + q4*8);
                // cw = silu(m2@Wc1 + cb1) . w2c  (accumulate cols in-register across ntiles)
                float cwp[4] = {0.f,0.f,0.f,0.f};
#pragma unroll
                for (int nt = 0; nt < 4; ++nt) {
                    v4f acc = {0.f,0.f,0.f,0.f};
                    acc = __builtin_amdgcn_mfma_f32_16x16x32_bf16(c0, wc1f[nt*2+0], acc, 0,0,0);
                    acc = __builtin_amdgcn_mfma_f32_16x16x32_bf16(c1, wc1f[nt*2+1], acc, 0,0,0);
#pragma unroll
                    for (int reg = 0; reg < 4; ++reg)
                        cwp[reg] += silu_f(acc[reg] + cb1_v[nt]) * w2c_v[nt];
                }
#pragma unroll
                for (int reg = 0; reg < 4; ++reg) {
                    float v = cwp[reg];
                    v += __shfl_xor(v, 1); v += __shfl_xor(v, 2);
                    v += __shfl_xor(v, 4); v += __shfl_xor(v, 8);
                    int e = e0 + q4*4 + reg;
                    if (c16 < 3) {
                        int src = s_esrc[e];
                        atomicAdd(&s_shift[src*3 + c16], s_endc[e*3 + c16] * v);
                    }
                }
            }
            // m_i -> bf16 into habf cols 64..127 (own rows)
#pragma unroll
            for (int r = 0; r < 8; ++r) {
                int d = wave*8 + r;
                s_habf[d*136 + 64 + lane] = f2bf(s_mi[d*64 + lane]);
            }
        }
        __syncthreads();    // B3: habf m_i part visible

        // ---- node GEMM1: n1 = silu([h|mi]@Wn1 + nb), wave w -> ntile w ----
        {
            s8v b[4];
#pragma unroll
            for (int kt = 0; kt < 4; ++kt)
                b[kt] = *(const s8v*)(wl + 16384 + ((wave*4+kt)*64 + lane)*8);
            int col = wave*16 + c16;
            float nbc = s_nb[col];
#pragma unroll
            for (int mt = 0; mt < 2; ++mt) {
                v4f acc = {0.f,0.f,0.f,0.f};
#pragma unroll
                for (int kt = 0; kt < 4; ++kt) {
                    s8v a = *(const s8v*)(s_habf + (mt*16 + c16)*136 + kt*32 + q4*8);
                    acc = __builtin_amdgcn_mfma_f32_16x16x32_bf16(a, b[kt], acc, 0,0,0);
                }
#pragma unroll
                for (int reg = 0; reg < 4; ++reg) {
                    int row = mt*16 + q4*4 + reg;
                    s_n1bf[row*72 + col] = f2bf(silu_f(acc[reg] + nbc));
                }
            }
        }
        __syncthreads();    // B4: n1 visible

        // ---- node GEMM2: h += n1@Wn2 + b2 ----
        {
            s8v b0 = *(const s8v*)(wl + 24576 + ((wave*2+0)*64 + lane)*8);
            s8v b1 = *(const s8v*)(wl + 24576 + ((wave*2+1)*64 + lane)*8);
            int col = wave*16 + c16;
#pragma unroll
            for (int mt = 0; mt < 2; ++mt) {
                s8v a0 = *(const s8v*)(s_n1bf + (mt*16 + c16)*72 +      q4*8);
                s8v a1 = *(const s8v*)(s_n1bf + (mt*16 + c16)*72 + 32 + q4*8);
                v4f acc = {0.f,0.f,0.f,0.f};
                acc = __builtin_amdgcn_mfma_f32_16x16x32_bf16(a0, b0, acc, 0,0,0);
                acc = __builtin_amdgcn_mfma_f32_16x16x32_bf16(a1, b1, acc, 0,0,0);
#pragma unroll
                for (int reg = 0; reg < 4; ++reg) {
                    int row = mt*16 + q4*4 + reg;
                    float hn = s_h[row*64 + col] + acc[reg] + nb2_v;
                    s_h[row*64 + col] = hn;
                    s_habf[row*136 + col] = f2bf(hn);
                }
            }
        }
        __syncthreads();    // B5 = next layer's precondition
    }

    // ---------------- epilogue ----------------
    if (tid == 0) {
        float a=s_lat[0],b=s_lat[1],cc=s_lat[2];
        float d=s_lat[3],e=s_lat[4],f =s_lat[5];
        float g=s_lat[6],h2=s_lat[7],i2=s_lat[8];
        float A  =  (e*i2 - f*h2);
        float Bm = -(d*i2 - f*g);
        float C  =  (d*h2 - e*g);
        float det = a*A + b*Bm + cc*C;
        float rd = 1.0f/det;
        s_inv[0] = A*rd;
        s_inv[1] = -(b*i2 - cc*h2)*rd;
        s_inv[2] =  (b*f  - cc*e )*rd;
        s_inv[3] = Bm*rd;
        s_inv[4] =  (a*i2 - cc*g )*rd;
        s_inv[5] = -(a*f  - cc*d )*rd;
        s_inv[6] = C*rd;
        s_inv[7] = -(a*h2 - b*g  )*rd;
        s_inv[8] =  (a*e  - b*d  )*rd;
    }
    __syncthreads();
    if (tid < 96) {
        int r = tid/3, j = tid%3;
        float v = s_shift[r*3+0]*s_inv[0*3+j]
                + s_shift[r*3+1]*s_inv[1*3+j]
                + s_shift[r*3+2]*s_inv[2*3+j];
        out[(base + r)*3 + j] = v;
    }
    for (int q = tid; q < 2048; q += 256) {
        out[NN*3 + base*64 + q] = s_h[q];
    }
}

extern "C" void kernel_launch(void* const* d_in, const int* in_sizes, int n_in,
                              void* d_out, int out_size, void* d_ws, size_t ws_size,
                              hipStream_t stream) {
    unsigned short* wbf = (unsigned short*)d_ws;
    prepack_w<<<(4*WPL + 255)/256, 256, 0, stream>>>(
        (const float*)d_in[12], (const float*)d_in[14], (const float*)d_in[16],
        (const float*)d_in[19], (const float*)d_in[21], wbf);
    crystal_fused<<<NB, 256, 0, stream>>>(
        (const float*)d_in[0],  (const float*)d_in[1],  (const float*)d_in[2],  (const float*)d_in[3],
        (const float*)d_in[6],  (const float*)d_in[7],  (const float*)d_in[8],  (const float*)d_in[9],
        (const float*)d_in[10], (const float*)d_in[11],
        (const float*)d_in[12], (const float*)d_in[13], (const float*)d_in[15],
        (const float*)d_in[17], (const float*)d_in[18],
        (const float*)d_in[19], (const float*)d_in[20], (const float*)d_in[22],
        wbf, (float*)d_out);
}